// Round 6
// baseline (828.390 us; speedup 1.0000x reference)
//
#include <hip/hip_runtime.h>
#include <hip/hip_fp16.h>

// Problem constants (fixed by the reference)
constexpr int Bb = 32;     // batch
constexpr int Tt = 32;     // time steps
constexpr int Ii = 8192;   // input dim
constexpr int Hh = 8192;   // hidden dim
constexpr int Oo = 2048;   // output dim
constexpr int TB = Tt * Bb;  // halves per x2 column = 1024
constexpr int TCH = 4;       // timesteps per XCD chunk
constexpr int TILE = 4096;   // COO entries per radix tile
constexpr int NB = 8;        // row-range buckets (= XCD count)

// Entry packing: lo16 = col (u16), hi16 = fp16 value bits. 4 B/entry.
// Rows padded to multiples of 8 entries (32 B) -> int4 loads cover 4 entries.
//
// Journal of failed experiments (do not retry):
//  - R1: XCD row-partitioned single-pass scatter: 8x COO re-scan -> +74 MB
//    FETCH, L2 thrash kept write amp (94->64 MB only). Regressed 117->164 us.
//  - R2: all-32-step cooperative kernel w/ grid.sync(): ~280 us PER SYNC at
//    2048 blocks. 24x regression. Dispatch boundaries are the cheap sync.
//  - R3/R4: __builtin_nontemporal_load build -> container failed twice
//    (correlation n=2). Avoid the NT builtin.

__device__ __forceinline__ float entval(uint32_t u) {
  return __half2float(__ushort_as_half((unsigned short)(u >> 16)));
}

// ---------------- x transpose: (B,T,I) fp32 -> (I,T,B) fp16 ----------------
__global__ void transpose_x_kernel(const float* __restrict__ x, __half2* __restrict__ x2) {
  int blk = blockIdx.x;          // (Tt/2) * (Ii/64) = 2048 blocks
  int tp = blk >> 7;
  int ib = blk & 127;
  int t0 = tp * 2;
  int i0 = ib * 64;
  __shared__ float lds[64][65];
  int tid = threadIdx.x;
  for (int idx = tid; idx < 64 * 64; idx += 256) {
    int row = idx >> 6, il = idx & 63;     // coalesced reads along i
    int tt = row >> 5, bb = row & 31;
    lds[il][row] = x[(size_t)bb * Tt * Ii + (size_t)(t0 + tt) * Ii + i0 + il];
  }
  __syncthreads();
  for (int idx = tid; idx < 64 * 32; idx += 256) {
    int il = idx >> 5;
    int q = idx & 31;
    int tt = q >> 4, p = q & 15;           // b-pair p -> batches 2p, 2p+1
    float lo = lds[il][tt * 32 + 2 * p];
    float hi = lds[il][tt * 32 + 2 * p + 1];
    x2[(size_t)(i0 + il) * (TB / 2) + (size_t)(t0 + tt) * 16 + p] = __floats2half2_rn(lo, hi);
  }
}

// ---------------- CSR build: 3-phase radix partition ----------------
// Phase 1: per-row histogram (CSR counts) + per-(tile,bucket) counts.
// One block per 4096-entry tile. bucket = row >> shift (8 row-range octants).
__global__ void __launch_bounds__(256) count_kernel(
    const int* __restrict__ r1, int n1, int* __restrict__ cu1, int* __restrict__ tb1, int nt1,
    const int* __restrict__ r2, int n2, int* __restrict__ cu2, int* __restrict__ tb2, int nt2,
    const int* __restrict__ r3, int n3, int* __restrict__ cu3, int* __restrict__ tb3) {
  __shared__ int cnt[NB];
  int tile = blockIdx.x;
  const int* rows; int n; int* cur; int* tb; int tl; int shift;
  if (tile < nt1)            { rows = r1; n = n1; cur = cu1; tb = tb1; tl = tile;             shift = 10; }
  else if (tile < nt1 + nt2) { rows = r2; n = n2; cur = cu2; tb = tb2; tl = tile - nt1;       shift = 10; }
  else                       { rows = r3; n = n3; cur = cu3; tb = tb3; tl = tile - nt1 - nt2; shift = 8;  }
  if (threadIdx.x < NB) cnt[threadIdx.x] = 0;
  __syncthreads();
  int base = tl * TILE;
  for (int k = threadIdx.x; k < TILE; k += 256) {
    int j = base + k;
    if (j < n) {
      int rr = rows[j];
      atomicAdd(&cur[rr], 1);               // CSR row histogram (as old hist3)
      atomicAdd(&cnt[rr >> shift], 1);      // tile-bucket count
    }
  }
  __syncthreads();
  if (threadIdx.x < NB) tb[tl * NB + threadIdx.x] = cnt[threadIdx.x];
}

// Phase 2: blocks 0-2 = CSR exclusive scan (counts -> 8-padded row starts,
// cursor init), blocks 3-5 = bucket-major exclusive scan of tile counts ->
// exact (tile,bucket) placement offsets + per-bucket bases bb[9].
__global__ void scan6_kernel(int* __restrict__ c1, int n1, int* __restrict__ r1,
                             int* __restrict__ c2, int n2, int* __restrict__ r2,
                             int* __restrict__ c3, int n3, int* __restrict__ r3,
                             int* __restrict__ tb1, int nt1, int* __restrict__ bb1,
                             int* __restrict__ tb2, int nt2, int* __restrict__ bb2,
                             int* __restrict__ tb3, int nt3, int* __restrict__ bb3) {
  __shared__ int sums[1024];
  __shared__ int totals[NB];
  __shared__ int bases[NB];
  int bx = blockIdx.x;
  int tid = threadIdx.x;
  if (bx < 3) {
    int* cnt_cursor; int n; int* row_start;
    if (bx == 0)      { cnt_cursor = c1; n = n1; row_start = r1; }
    else if (bx == 1) { cnt_cursor = c2; n = n2; row_start = r2; }
    else              { cnt_cursor = c3; n = n3; row_start = r3; }
    int chunk = (n + 1023) >> 10;
    int base = tid * chunk;
    int s = 0;
    for (int i = 0; i < chunk; i++) {
      int idx = base + i;
      if (idx < n) s += (cnt_cursor[idx] + 7) & ~7;
    }
    sums[tid] = s;
    __syncthreads();
    for (int off = 1; off < 1024; off <<= 1) {
      int other = (tid >= off) ? sums[tid - off] : 0;
      __syncthreads();
      sums[tid] += other;
      __syncthreads();
    }
    int run = sums[tid] - s;
    for (int i = 0; i < chunk; i++) {
      int idx = base + i;
      if (idx < n) {
        int v = cnt_cursor[idx];
        row_start[idx] = run;
        cnt_cursor[idx] = run;
        run += (v + 7) & ~7;
      }
    }
    if (tid == 1023) row_start[n] = sums[1023];
  } else {
    int m = bx - 3;
    int* tb; int nt; int* bb;
    if (m == 0)      { tb = tb1; nt = nt1; bb = bb1; }
    else if (m == 1) { tb = tb2; nt = nt2; bb = bb2; }
    else             { tb = tb3; nt = nt3; bb = bb3; }
    if (tid < NB) {
      int run = 0;
      for (int t = 0; t < nt; t++) {
        int v = tb[t * NB + tid];
        tb[t * NB + tid] = run;
        run += v;
      }
      totals[tid] = run;
    }
    __syncthreads();
    if (tid == 0) {
      int acc = 0;
      for (int k = 0; k < NB; k++) { bases[k] = acc; bb[k] = acc; acc += totals[k]; }
      bb[NB] = acc;
    }
    __syncthreads();
    if (tid < NB) {
      int add = bases[tid];
      for (int t = 0; t < nt; t++) tb[t * NB + tid] += add;
    }
  }
}

// Phase 3: place entries into dense per-bucket streams (u64 = entry<<32 | row).
// Each block writes contiguous per-(tile,bucket) segments -> full 64B lines
// from a single L2 (no cross-XCD partial-line writebacks). Rank within a
// (tile,bucket) is arrival-order (LDS atomic) -- CSR entry order within a row
// is irrelevant (duplicates sum commutatively).
__global__ void __launch_bounds__(256) place_kernel(
    const int* __restrict__ r1, const int* __restrict__ c1, const float* __restrict__ v1,
    int n1, const int* __restrict__ tb1, int nt1, uint64_t* __restrict__ s1,
    const int* __restrict__ r2, const int* __restrict__ c2, const float* __restrict__ v2,
    int n2, const int* __restrict__ tb2, int nt2, uint64_t* __restrict__ s2,
    const int* __restrict__ r3, const int* __restrict__ c3, const float* __restrict__ v3,
    int n3, const int* __restrict__ tb3, uint64_t* __restrict__ s3) {
  __shared__ int off[NB];
  __shared__ int cnt[NB];
  int tile = blockIdx.x;
  const int* rows; const int* cols; const float* vals; int n;
  const int* tb; uint64_t* st; int tl; int shift;
  if (tile < nt1)            { rows = r1; cols = c1; vals = v1; n = n1; tb = tb1; st = s1; tl = tile;             shift = 10; }
  else if (tile < nt1 + nt2) { rows = r2; cols = c2; vals = v2; n = n2; tb = tb2; st = s2; tl = tile - nt1;       shift = 10; }
  else                       { rows = r3; cols = c3; vals = v3; n = n3; tb = tb3; st = s3; tl = tile - nt1 - nt2; shift = 8;  }
  if (threadIdx.x < NB) { off[threadIdx.x] = tb[tl * NB + threadIdx.x]; cnt[threadIdx.x] = 0; }
  __syncthreads();
  int base = tl * TILE;
  for (int k = threadIdx.x; k < TILE; k += 256) {
    int j = base + k;
    if (j < n) {
      int rr = rows[j];
      uint32_t ent = ((uint32_t)__half_as_ushort(__float2half_rn(vals[j])) << 16) | (uint32_t)cols[j];
      int b = rr >> shift;
      int rank = atomicAdd(&cnt[b], 1);
      st[(size_t)(off[b] + rank)] = ((uint64_t)ent << 32) | (uint32_t)rr;
    }
  }
}

// Phase 4: partition-local scatter. Partition p = blockIdx&7 (XCD heuristic)
// reads ONLY bucket p (contiguous ~1/8 slice) and scatters to its own row
// range: cursor atomics + entry writes stay in one XCD's L2 with only ~2 MB
// of streaming pressure -> entry lines assemble fully before writeback.
__global__ void __launch_bounds__(256) bscatter_kernel(
    const uint64_t* __restrict__ s1, const int* __restrict__ bb1, int* __restrict__ cu1, uint32_t* __restrict__ e1,
    const uint64_t* __restrict__ s2, const int* __restrict__ bb2, int* __restrict__ cu2, uint32_t* __restrict__ e2,
    const uint64_t* __restrict__ s3, const int* __restrict__ bb3, int* __restrict__ cu3, uint32_t* __restrict__ e3) {
  int p = blockIdx.x & 7;
  int wid = (int)(blockIdx.x >> 3) * 256 + threadIdx.x;
  int stride = (int)(gridDim.x >> 3) * 256;
  {
    int lo = bb1[p], hi = bb1[p + 1];
    for (int j = lo + wid; j < hi; j += stride) {
      uint64_t e = s1[j];
      int rr = (int)(uint32_t)e;
      int pos = atomicAdd(&cu1[rr], 1);
      e1[pos] = (uint32_t)(e >> 32);
    }
  }
  {
    int lo = bb2[p], hi = bb2[p + 1];
    for (int j = lo + wid; j < hi; j += stride) {
      uint64_t e = s2[j];
      int rr = (int)(uint32_t)e;
      int pos = atomicAdd(&cu2[rr], 1);
      e2[pos] = (uint32_t)(e >> 32);
    }
  }
  {
    int lo = bb3[p], hi = bb3[p + 1];
    for (int j = lo + wid; j < hi; j += stride) {
      uint64_t e = s3[j];
      int rr = (int)(uint32_t)e;
      int pos = atomicAdd(&cu3[rr], 1);
      e3[pos] = (uint32_t)(e >> 32);
    }
  }
}

// ---------------- preIH, XCD-pinned time chunks, fp16 data ----------------
// xcd = blockIdx&7 owns t-chunk [4*xcd, 4*xcd+4): 2 MB fp16 x2 slice L2-resident.
// Lane covers (tt = lane>>4, b-pair = lane&15); gather = uint (2 fp16) -> 256 B/entry.
__global__ void __launch_bounds__(256, 8) preih_kernel(
    const int* __restrict__ ih_rs, const int* __restrict__ ih_cur,
    const uint32_t* __restrict__ ih_ent,
    const float* __restrict__ hh_bias, const __half* __restrict__ x2h,
    __half2* __restrict__ preAll) {
  int xcd = blockIdx.x & 7;
  int r = ((blockIdx.x >> 3) << 2) + (threadIdx.x >> 6);
  int lane = threadIdx.x & 63;
  int t0 = xcd * TCH;
  int s0  = __builtin_amdgcn_readfirstlane(ih_rs[r]);       // multiple of 8
  int cnt = __builtin_amdgcn_readfirstlane(ih_cur[r]) - s0;
  int nb = (cnt + 7) >> 3;                                  // 8-entry blocks
  const int4* ep = (const int4*)(ih_ent + s0);
  const uint32_t* xb = (const uint32_t*)(x2h + (size_t)t0 * Bb);  // + c*(TB/2) uints

  float2 a0 = {0.f, 0.f}, a1 = {0.f, 0.f}, a2 = {0.f, 0.f}, a3 = {0.f, 0.f};
  int4 f0 = ep[0], f1 = ep[1];
  for (int i = 0; i < nb; i++) {
    int4 e0 = f0, e1 = f1;
    f0 = ep[2 * i + 2];            // prefetch next block during gathers
    f1 = ep[2 * i + 3];
    uint32_t u0 = (uint32_t)e0.x, u1 = (uint32_t)e0.y, u2 = (uint32_t)e0.z, u3 = (uint32_t)e0.w;
    uint32_t u4 = (uint32_t)e1.x, u5 = (uint32_t)e1.y, u6 = (uint32_t)e1.z, u7 = (uint32_t)e1.w;
    uint32_t g0 = xb[(size_t)(u0 & 0xffff) * (TB / 2) + lane];
    uint32_t g1 = xb[(size_t)(u1 & 0xffff) * (TB / 2) + lane];
    uint32_t g2 = xb[(size_t)(u2 & 0xffff) * (TB / 2) + lane];
    uint32_t g3 = xb[(size_t)(u3 & 0xffff) * (TB / 2) + lane];
    uint32_t g4 = xb[(size_t)(u4 & 0xffff) * (TB / 2) + lane];
    uint32_t g5 = xb[(size_t)(u5 & 0xffff) * (TB / 2) + lane];
    uint32_t g6 = xb[(size_t)(u6 & 0xffff) * (TB / 2) + lane];
    uint32_t g7 = xb[(size_t)(u7 & 0xffff) * (TB / 2) + lane];
    float v0 = entval(u0), v1 = entval(u1), v2 = entval(u2), v3 = entval(u3);
    float v4 = entval(u4), v5 = entval(u5), v6 = entval(u6), v7 = entval(u7);
    float2 x0 = __half22float2(*(__half2*)&g0), x1 = __half22float2(*(__half2*)&g1);
    float2 x2v = __half22float2(*(__half2*)&g2), x3 = __half22float2(*(__half2*)&g3);
    float2 x4 = __half22float2(*(__half2*)&g4), x5 = __half22float2(*(__half2*)&g5);
    float2 x6 = __half22float2(*(__half2*)&g6), x7 = __half22float2(*(__half2*)&g7);
    a0.x += v0 * x0.x;  a0.y += v0 * x0.y;   a0.x += v4 * x4.x;  a0.y += v4 * x4.y;
    a1.x += v1 * x1.x;  a1.y += v1 * x1.y;   a1.x += v5 * x5.x;  a1.y += v5 * x5.y;
    a2.x += v2 * x2v.x; a2.y += v2 * x2v.y;  a2.x += v6 * x6.x;  a2.y += v6 * x6.y;
    a3.x += v3 * x3.x;  a3.y += v3 * x3.y;   a3.x += v7 * x7.x;  a3.y += v7 * x7.y;
  }
  float bias = hh_bias[r];
  float sx = ((a0.x + a1.x) + (a2.x + a3.x)) + bias;
  float sy = ((a0.y + a1.y) + (a2.y + a3.y)) + bias;
  int tt = lane >> 4, p = lane & 15;
  preAll[((size_t)(t0 + tt) * Hh + r) * 16 + p] = __floats2half2_rn(sx, sy);
}

// ---------------- One recurrence step: h_{t+1} = sigmoid(pre_t + HH @ h_t) ----------------
// One wave per row; fp16 h/pre, packed 4B entries, entry prefetch.
__global__ void __launch_bounds__(256, 8) step_kernel(
    const int* __restrict__ hh_rs, const int* __restrict__ hh_cur,
    const uint32_t* __restrict__ hh_ent,
    const __half* __restrict__ pre_t,
    const __half* __restrict__ hprev,
    __half* __restrict__ hnext) {
  int r = (blockIdx.x * 256 + threadIdx.x) >> 6;
  int lane = threadIdx.x & 63;
  int h = lane >> 5, b = lane & 31;
  int s0  = __builtin_amdgcn_readfirstlane(hh_rs[r]);       // multiple of 8
  int cnt = __builtin_amdgcn_readfirstlane(hh_cur[r]) - s0;
  int nb = (cnt + 7) >> 3;
  const int4* ep = (const int4*)(hh_ent + s0);
  float pre = __half2float(pre_t[(r << 5) + b]);

  float a0 = 0.f, a1 = 0.f, a2 = 0.f, a3 = 0.f;
  int4 f0 = ep[0], f1 = ep[1];
  for (int i = 0; i < nb; i++) {
    int4 e0 = f0, e1 = f1;
    f0 = ep[2 * i + 2];
    f1 = ep[2 * i + 3];
    uint32_t u0 = (uint32_t)(h ? e0.y : e0.x);   // parity split across half-waves
    uint32_t u1 = (uint32_t)(h ? e0.w : e0.z);
    uint32_t u2 = (uint32_t)(h ? e1.y : e1.x);
    uint32_t u3 = (uint32_t)(h ? e1.w : e1.z);
    float h0 = __half2float(hprev[(((size_t)(u0 & 0xffff)) << 5) + b]);
    float h1 = __half2float(hprev[(((size_t)(u1 & 0xffff)) << 5) + b]);
    float h2 = __half2float(hprev[(((size_t)(u2 & 0xffff)) << 5) + b]);
    float h3 = __half2float(hprev[(((size_t)(u3 & 0xffff)) << 5) + b]);
    a0 += entval(u0) * h0;
    a1 += entval(u1) * h1;
    a2 += entval(u2) * h2;
    a3 += entval(u3) * h3;
  }
  float acc = (a0 + a1) + (a2 + a3);
  acc += __shfl_xor(acc, 32, 64);
  float hv = 1.0f / (1.0f + __expf(-(pre + acc)));
  if (h == 0) hnext[(r << 5) + b] = __float2half_rn(hv);
}

// ---------------- Output spmm, XCD-partitioned by time, fp16 h ----------------
__global__ void __launch_bounds__(256, 8) out_kernel(
    const int* __restrict__ ho_rs, const int* __restrict__ ho_cur,
    const uint32_t* __restrict__ ho_ent,
    const float* __restrict__ ho_bias, const __half* __restrict__ hAll,
    float* __restrict__ out_tmp) {
  int xcd = blockIdx.x & 7;
  int w   = (blockIdx.x >> 3) * 4 + (threadIdx.x >> 6);
  int lane = threadIdx.x & 63;
  int h = lane >> 5, b = lane & 31;
  int t0 = xcd * 4;
  constexpr size_t HS = (size_t)Hh * Bb;
  const __half* hbase = hAll + (size_t)(t0 + 1) * HS;

  for (int o = w; o < Oo; o += 1024) {
    int s0  = __builtin_amdgcn_readfirstlane(ho_rs[o]);
    int cnt = __builtin_amdgcn_readfirstlane(ho_cur[o]) - s0;
    int nb = (cnt + 7) >> 3;
    const int4* ep = (const int4*)(ho_ent + s0);
    float bias = (h == 0) ? ho_bias[o] : 0.f;
    float A0 = bias, A1 = bias, A2 = bias, A3 = bias;
    float B0 = 0.f, B1 = 0.f, B2 = 0.f, B3 = 0.f;
    for (int i = 0; i < nb; i++) {
      int4 e0 = ep[2 * i], e1 = ep[2 * i + 1];
      uint32_t u0 = (uint32_t)(h ? e0.y : e0.x);
      uint32_t u1 = (uint32_t)(h ? e0.w : e0.z);
      uint32_t u2 = (uint32_t)(h ? e1.y : e1.x);
      uint32_t u3 = (uint32_t)(h ? e1.w : e1.z);
      const __half* p0 = hbase + (((size_t)(u0 & 0xffff)) << 5) + b;
      const __half* p1 = hbase + (((size_t)(u1 & 0xffff)) << 5) + b;
      const __half* p2 = hbase + (((size_t)(u2 & 0xffff)) << 5) + b;
      const __half* p3 = hbase + (((size_t)(u3 & 0xffff)) << 5) + b;
      float v0 = entval(u0), v1 = entval(u1), v2 = entval(u2), v3 = entval(u3);
      A0 += v0 * __half2float(p0[0]);
      A1 += v0 * __half2float(p0[HS]);
      A2 += v0 * __half2float(p0[2 * HS]);
      A3 += v0 * __half2float(p0[3 * HS]);
      B0 += v1 * __half2float(p1[0]);
      B1 += v1 * __half2float(p1[HS]);
      B2 += v1 * __half2float(p1[2 * HS]);
      B3 += v1 * __half2float(p1[3 * HS]);
      A0 += v2 * __half2float(p2[0]);
      A1 += v2 * __half2float(p2[HS]);
      A2 += v2 * __half2float(p2[2 * HS]);
      A3 += v2 * __half2float(p2[3 * HS]);
      B0 += v3 * __half2float(p3[0]);
      B1 += v3 * __half2float(p3[HS]);
      B2 += v3 * __half2float(p3[2 * HS]);
      B3 += v3 * __half2float(p3[3 * HS]);
    }
    A0 += B0; A1 += B1; A2 += B2; A3 += B3;
    A0 += __shfl_xor(A0, 32, 64);
    A1 += __shfl_xor(A1, 32, 64);
    A2 += __shfl_xor(A2, 32, 64);
    A3 += __shfl_xor(A3, 32, 64);
    if (h == 0) {
      out_tmp[((size_t)(t0 + 0) * Oo + o) * Bb + b] = A0;
      out_tmp[((size_t)(t0 + 1) * Oo + o) * Bb + b] = A1;
      out_tmp[((size_t)(t0 + 2) * Oo + o) * Bb + b] = A2;
      out_tmp[((size_t)(t0 + 3) * Oo + o) * Bb + b] = A3;
    }
  }
}

// ---------------- out transpose: (T,O,B) -> (B,T,O), fp32 ----------------
__global__ void transpose_out_kernel(const float* __restrict__ out_tmp, float* __restrict__ dout) {
  int blk = blockIdx.x;
  int t  = blk >> 5;
  int o0 = (blk & 31) << 6;
  __shared__ float lds[64][33];
  int tid = threadIdx.x;
  for (int idx = tid; idx < 64 * 32; idx += 256) {
    int ol = idx >> 5, bb = idx & 31;
    lds[ol][bb] = out_tmp[(size_t)t * Oo * Bb + (size_t)(o0 + ol) * Bb + bb];
  }
  __syncthreads();
  for (int idx = tid; idx < 32 * 64; idx += 256) {
    int bb = idx >> 6, ol = idx & 63;
    dout[(size_t)bb * Tt * Oo + (size_t)t * Oo + o0 + ol] = lds[ol][bb];
  }
}

extern "C" void kernel_launch(void* const* d_in, const int* in_sizes, int n_in,
                              void* d_out, int out_size, void* d_ws, size_t ws_size,
                              hipStream_t stream) {
  const float* x       = (const float*)d_in[0];
  const int*   hh_rows = (const int*)d_in[1];
  const int*   hh_cols = (const int*)d_in[2];
  const float* hh_vals = (const float*)d_in[3];
  const float* hh_bias = (const float*)d_in[4];
  const int*   ih_rows = (const int*)d_in[5];
  const int*   ih_cols = (const int*)d_in[6];
  const float* ih_vals = (const float*)d_in[7];
  const int*   ho_rows = (const int*)d_in[8];
  const int*   ho_cols = (const int*)d_in[9];
  const float* ho_vals = (const float*)d_in[10];
  const float* ho_bias = (const float*)d_in[11];
  float* out = (float*)d_out;

  const int nnz_hh = in_sizes[1];
  const int nnz_ih = in_sizes[5];
  const int nnz_ho = in_sizes[8];

  const int ntile_ih = (nnz_ih + TILE - 1) / TILE;
  const int ntile_hh = (nnz_hh + TILE - 1) / TILE;
  const int ntile_ho = (nnz_ho + TILE - 1) / TILE;

  // Workspace carve-up (~70 MB)
  char* w = (char*)d_ws;
  size_t off = 0;
  auto alloc = [&](size_t bytes) -> void* {
    void* p = w + off;
    off += (bytes + 255) & ~(size_t)255;
    return p;
  };
  __half* x2h    = (__half*)alloc(2 * (size_t)Ii * TB);                 // 16 MB
  __half* hAll   = (__half*)alloc(2 * (size_t)(Tt + 1) * Hh * Bb);      // 16.5 MB
  __half* preAll = (__half*)alloc(2 * (size_t)Tt * Hh * Bb);            // 16 MB
  float* out_tmp = (float*)alloc(4 * (size_t)Tt * Oo * Bb);             // 8 MB
  int*  ih_rs  = (int*)alloc(4 * (size_t)(Hh + 1));
  int*  hh_rs  = (int*)alloc(4 * (size_t)(Hh + 1));
  int*  ho_rs  = (int*)alloc(4 * (size_t)(Oo + 1));
  size_t zero_off0 = off;
  int*  cur_all = (int*)alloc(4 * (size_t)(Hh + Hh + Oo));
  int*  ih_cur = cur_all;
  int*  hh_cur = cur_all + Hh;
  int*  ho_cur = cur_all + 2 * Hh;
  size_t zero_bytes = off - zero_off0;
  size_t ent_off0 = off;
  uint32_t* ih_ent = (uint32_t*)alloc(4 * ((size_t)nnz_ih + 8 * Hh + 64));  // pad8 + slack
  uint32_t* hh_ent = (uint32_t*)alloc(4 * ((size_t)nnz_hh + 8 * Hh + 64));
  uint32_t* ho_ent = (uint32_t*)alloc(4 * ((size_t)nnz_ho + 8 * Oo + 64));
  size_t ent_bytes = off - ent_off0;
  // radix bookkeeping (fully written each run -> no memset needed)
  int* tb_ih  = (int*)alloc(4 * (size_t)(ntile_ih * NB));
  int* tb_hh  = (int*)alloc(4 * (size_t)(ntile_hh * NB));
  int* tb_ho  = (int*)alloc(4 * (size_t)(ntile_ho * NB));
  int* bb_all = (int*)alloc(4 * 27);   // 3 x 9 bucket bases

  // Bucket streams overlay preAll (14.7 MB <= 16 MB): consumed by bscatter
  // BEFORE preih writes preAll. u64 = entry<<32 | row.
  uint64_t* s_ih = (uint64_t*)preAll;
  uint64_t* s_hh = s_ih + (size_t)nnz_ih;
  uint64_t* s_ho = s_hh + (size_t)nnz_hh;

  // Init (3 memsets)
  hipMemsetAsync(hAll, 0, 2 * (size_t)Hh * Bb, stream);   // h_{-1} = 0 (fp16 zeros)
  hipMemsetAsync(w + zero_off0, 0, zero_bytes, stream);
  hipMemsetAsync(w + ent_off0, 0, ent_bytes, stream);     // pad entries = col 0, val 0

  // x -> (I,T,B) fp16
  transpose_x_kernel<<<(Tt / 2) * (Ii / 64), 256, 0, stream>>>(x, (__half2*)x2h);

  // CSR build, 3-phase radix partition
  count_kernel<<<ntile_ih + ntile_hh + ntile_ho, 256, 0, stream>>>(
      ih_rows, nnz_ih, ih_cur, tb_ih, ntile_ih,
      hh_rows, nnz_hh, hh_cur, tb_hh, ntile_hh,
      ho_rows, nnz_ho, ho_cur, tb_ho);
  scan6_kernel<<<6, 1024, 0, stream>>>(
      ih_cur, Hh, ih_rs, hh_cur, Hh, hh_rs, ho_cur, Oo, ho_rs,
      tb_ih, ntile_ih, bb_all, tb_hh, ntile_hh, bb_all + 9, tb_ho, ntile_ho, bb_all + 18);
  place_kernel<<<ntile_ih + ntile_hh + ntile_ho, 256, 0, stream>>>(
      ih_rows, ih_cols, ih_vals, nnz_ih, tb_ih, ntile_ih, s_ih,
      hh_rows, hh_cols, hh_vals, nnz_hh, tb_hh, ntile_hh, s_hh,
      ho_rows, ho_cols, ho_vals, nnz_ho, tb_ho, s_ho);
  bscatter_kernel<<<2048, 256, 0, stream>>>(
      s_ih, bb_all, ih_cur, ih_ent,
      s_hh, bb_all + 9, hh_cur, hh_ent,
      s_ho, bb_all + 18, ho_cur, ho_ent);

  // pre[t][r][b] fp16, XCD-pinned time chunks
  preih_kernel<<<8 * Hh / 4, 256, 0, stream>>>(
      ih_rs, ih_cur, ih_ent, hh_bias, x2h, (__half2*)preAll);

  // Recurrence: one dispatch per step
  for (int t = 0; t < Tt; t++) {
    step_kernel<<<Hh / 4, 256, 0, stream>>>(
        hh_rs, hh_cur, hh_ent,
        preAll + (size_t)t * Hh * Bb,
        hAll + (size_t)t * Hh * Bb,
        hAll + (size_t)(t + 1) * Hh * Bb);
  }

  // Output spmm (XCD t-partitioned) + final transpose
  out_kernel<<<2048, 256, 0, stream>>>(
      ho_rs, ho_cur, ho_ent, ho_bias, hAll, out_tmp);
  transpose_out_kernel<<<Tt * (Oo / 64), 256, 0, stream>>>(out_tmp, out);

  (void)n_in; (void)out_size; (void)ws_size;
}